// Round 1
// baseline (558.431 us; speedup 1.0000x reference)
//
#include <hip/hip_runtime.h>
#include <hip/hip_fp16.h>

#define TT 7
#define DD 40
#define HH 64
#define FCC 32
#define ROWS 64   // batch rows per block
#define MR 8      // rows per wave
#define NTH 512   // 8 waves

__device__ __forceinline__ float RL(float v, int k) {
  return __int_as_float(__builtin_amdgcn_readlane(__float_as_int(v), k));
}
__device__ __forceinline__ float sigf(float x) {
  return 1.f / (1.f + __expf(-x));
}
__device__ __forceinline__ float tanhf_(float x) {
  // stable: x->+inf => 1, x->-inf => -1 (exp(2x)->inf => 2/inf=0; ->0 => 1-2=-1)
  return 1.f - 2.f / (__expf(2.f * x) + 1.f);
}

__global__ __launch_bounds__(NTH, 1) void lstm2_fused_kernel(
    const float* __restrict__ x,
    const float* __restrict__ Wih0, const float* __restrict__ Whh0,
    const float* __restrict__ bih0, const float* __restrict__ bhh0,
    const float* __restrict__ Wih1, const float* __restrict__ Whh1,
    const float* __restrict__ bih1, const float* __restrict__ bhh1,
    const float* __restrict__ W1, const float* __restrict__ b1,
    const float* __restrict__ W2, const float* __restrict__ b2,
    float* __restrict__ out)
{
  // LDS: 57344 + 65536 + 32768 = 155648 B  (<= 160 KiB, 1 block/CU)
  __shared__ unsigned short s_h1[TT * ROWS * HH];  // layer-0 output history, f16
  __shared__ float          s_wh[HH * HH * 4];     // recurrent weights, fp32, [k][j][g]
  __shared__ unsigned short s_wx[HH * HH * 4];     // input-side weights, f16, [k][j][g]

  const int tid   = threadIdx.x;
  const int wave  = tid >> 6;
  const int lane  = tid & 63;
  const int row0  = blockIdx.x * ROWS;
  const int wrow0 = row0 + wave * MR;

  // ---------------- Phase A: stage layer-0 weights ----------------
  for (int i = tid; i < 256 * HH; i += NTH) {      // Whh0 [256][64] -> [k][j][g] fp32
    int k = i & 63, r = i >> 6;
    int g = r >> 6, j = r & 63;
    s_wh[(k * 64 + j) * 4 + g] = Whh0[i];
  }
  for (int i = tid; i < 256 * DD; i += NTH) {      // Wih0 [256][40] -> [k][j][g] f16
    int k = i % DD, r = i / DD;
    int g = r >> 6, j = r & 63;
    s_wx[(k * 64 + j) * 4 + g] = __half_as_ushort(__float2half(Wih0[i]));
  }
  float bias[4];
  #pragma unroll
  for (int g = 0; g < 4; ++g) bias[g] = bih0[g * 64 + lane] + bhh0[g * 64 + lane];
  __syncthreads();

  float hA[MR], cA[MR];
  #pragma unroll
  for (int r = 0; r < MR; ++r) { hA[r] = 0.f; cA[r] = 0.f; }

  for (int t = 0; t < TT; ++t) {
    // x slice, lane-distributed: lane k holds x[row][t][k] (k < 40)
    float xr[MR];
    #pragma unroll
    for (int r = 0; r < MR; ++r)
      xr[r] = (lane < DD) ? x[(wrow0 + r) * (TT * DD) + t * DD + lane] : 0.f;

    float acc[4][MR];
    #pragma unroll
    for (int g = 0; g < 4; ++g)
      #pragma unroll
      for (int r = 0; r < MR; ++r) acc[g][r] = bias[g];

    // input contribution: K = 40
    #pragma unroll 4
    for (int k = 0; k < DD; ++k) {
      uint2 wp = *(const uint2*)&s_wx[(k * 64 + lane) * 4];
      float2 f0 = __half22float2(*(const __half2*)&wp.x);
      float2 f1 = __half22float2(*(const __half2*)&wp.y);
      #pragma unroll
      for (int r = 0; r < MR; ++r) {
        float s = RL(xr[r], k);
        acc[0][r] = fmaf(f0.x, s, acc[0][r]);
        acc[1][r] = fmaf(f0.y, s, acc[1][r]);
        acc[2][r] = fmaf(f1.x, s, acc[2][r]);
        acc[3][r] = fmaf(f1.y, s, acc[3][r]);
      }
    }
    // recurrent contribution: K = 64, fp32 weights
    #pragma unroll 4
    for (int k = 0; k < HH; ++k) {
      float4 w = *(const float4*)&s_wh[(k * 64 + lane) * 4];
      #pragma unroll
      for (int r = 0; r < MR; ++r) {
        float s = RL(hA[r], k);
        acc[0][r] = fmaf(w.x, s, acc[0][r]);
        acc[1][r] = fmaf(w.y, s, acc[1][r]);
        acc[2][r] = fmaf(w.z, s, acc[2][r]);
        acc[3][r] = fmaf(w.w, s, acc[3][r]);
      }
    }
    #pragma unroll
    for (int r = 0; r < MR; ++r) {
      float ig = sigf(acc[0][r]);
      float fg = sigf(acc[1][r]);
      float gg = tanhf_(acc[2][r]);
      float og = sigf(acc[3][r]);
      cA[r] = fg * cA[r] + ig * gg;
      hA[r] = og * tanhf_(cA[r]);
      s_h1[(t * ROWS + wave * MR + r) * HH + lane] =
          __half_as_ushort(__float2half(hA[r]));
    }
  }

  __syncthreads();
  // ---------------- Phase B: stage layer-1 weights ----------------
  for (int i = tid; i < 256 * HH; i += NTH) {      // Whh1 fp32
    int k = i & 63, r = i >> 6;
    int g = r >> 6, j = r & 63;
    s_wh[(k * 64 + j) * 4 + g] = Whh1[i];
  }
  for (int i = tid; i < 256 * HH; i += NTH) {      // Wih1 f16
    int k = i & 63, r = i >> 6;
    int g = r >> 6, j = r & 63;
    s_wx[(k * 64 + j) * 4 + g] = __half_as_ushort(__float2half(Wih1[i]));
  }
  #pragma unroll
  for (int g = 0; g < 4; ++g) bias[g] = bih1[g * 64 + lane] + bhh1[g * 64 + lane];
  __syncthreads();

  float hB[MR], cB[MR];
  #pragma unroll
  for (int r = 0; r < MR; ++r) { hB[r] = 0.f; cB[r] = 0.f; }

  for (int t = 0; t < TT; ++t) {
    // h1 slice, lane-distributed (within-wave rows only)
    float h1r[MR];
    #pragma unroll
    for (int r = 0; r < MR; ++r)
      h1r[r] = __half2float(__ushort_as_half(
          s_h1[(t * ROWS + wave * MR + r) * HH + lane]));

    float acc[4][MR];
    #pragma unroll
    for (int g = 0; g < 4; ++g)
      #pragma unroll
      for (int r = 0; r < MR; ++r) acc[g][r] = bias[g];

    #pragma unroll 4
    for (int k = 0; k < HH; ++k) {
      uint2 wp = *(const uint2*)&s_wx[(k * 64 + lane) * 4];
      float2 f0 = __half22float2(*(const __half2*)&wp.x);
      float2 f1 = __half22float2(*(const __half2*)&wp.y);
      float4 w = *(const float4*)&s_wh[(k * 64 + lane) * 4];
      #pragma unroll
      for (int r = 0; r < MR; ++r) {
        float s1 = RL(h1r[r], k);
        float s2 = RL(hB[r], k);
        acc[0][r] = fmaf(w.x, s2, acc[0][r]);
        acc[1][r] = fmaf(w.y, s2, acc[1][r]);
        acc[2][r] = fmaf(w.z, s2, acc[2][r]);
        acc[3][r] = fmaf(w.w, s2, acc[3][r]);
        acc[0][r] = fmaf(f0.x, s1, acc[0][r]);
        acc[1][r] = fmaf(f0.y, s1, acc[1][r]);
        acc[2][r] = fmaf(f1.x, s1, acc[2][r]);
        acc[3][r] = fmaf(f1.y, s1, acc[3][r]);
      }
    }
    #pragma unroll
    for (int r = 0; r < MR; ++r) {
      float ig = sigf(acc[0][r]);
      float fg = sigf(acc[1][r]);
      float gg = tanhf_(acc[2][r]);
      float og = sigf(acc[3][r]);
      cB[r] = fg * cB[r] + ig * gg;
      hB[r] = og * tanhf_(cB[r]);
    }
  }

  __syncthreads();
  // ---------------- Phase C: FC head on last h2 ----------------
  float* h2b  = (float*)s_wh;          // [64][64] = 16 KB (overlays weights)
  float* hidb = h2b + ROWS * HH;       // [64][32] =  8 KB
  #pragma unroll
  for (int r = 0; r < MR; ++r) h2b[(wave * MR + r) * HH + lane] = hB[r];
  __syncthreads();

  for (int i = tid; i < ROWS * FCC; i += NTH) {
    int row = i >> 5, fc = i & 31;
    float a = b1[fc];
    #pragma unroll
    for (int k = 0; k < HH; k += 4) {
      float4 hv = *(const float4*)&h2b[row * HH + k];
      float4 wv = *(const float4*)&W1[fc * HH + k];
      a += hv.x * wv.x + hv.y * wv.y + hv.z * wv.z + hv.w * wv.w;
    }
    hidb[row * FCC + fc] = fmaxf(a, 0.f);
  }
  __syncthreads();
  if (tid < ROWS) {
    float a = b2[0];
    #pragma unroll
    for (int k = 0; k < FCC; ++k) a += hidb[tid * FCC + k] * W2[k];
    out[row0 + tid] = a;
  }
}

extern "C" void kernel_launch(void* const* d_in, const int* in_sizes, int n_in,
                              void* d_out, int out_size, void* d_ws, size_t ws_size,
                              hipStream_t stream) {
  const float* x    = (const float*)d_in[0];
  const float* Wih0 = (const float*)d_in[1];
  const float* Whh0 = (const float*)d_in[2];
  const float* bih0 = (const float*)d_in[3];
  const float* bhh0 = (const float*)d_in[4];
  const float* Wih1 = (const float*)d_in[5];
  const float* Whh1 = (const float*)d_in[6];
  const float* bih1 = (const float*)d_in[7];
  const float* bhh1 = (const float*)d_in[8];
  const float* W1   = (const float*)d_in[9];
  const float* b1   = (const float*)d_in[10];
  const float* W2   = (const float*)d_in[11];
  const float* b2   = (const float*)d_in[12];
  float* out = (float*)d_out;

  const int B = in_sizes[0] / (TT * DD);   // 32768
  dim3 grid(B / ROWS), block(NTH);
  lstm2_fused_kernel<<<grid, block, 0, stream>>>(
      x, Wih0, Whh0, bih0, bhh0, Wih1, Whh1, bih1, bhh1, W1, b1, W2, b2, out);
}

// Round 2
// 139.869 us; speedup vs baseline: 3.9925x; 3.9925x over previous
//
#include <hip/hip_runtime.h>

#define TT 7
#define DD 40
#define HH 64
#define FCC 32
#define RB 64          // rows per block
#define NTH 512        // 8 waves = 2 row-halves x 4 j-quarters
#define LSTRIDE 68     // u32 stride of LDS h planes (pad: 2-way banks, 16B aligned)
#define PLANE (RB*LSTRIDE)

typedef _Float16 f16x8 __attribute__((ext_vector_type(8)));
typedef float f32x4 __attribute__((ext_vector_type(4)));

#define MFMA16(acc, a, b) acc = __builtin_amdgcn_mfma_f32_16x16x32_f16(a, b, acc, 0, 0, 0)

__device__ __forceinline__ float fast_rcp(float x) { return __builtin_amdgcn_rcpf(x); }
__device__ __forceinline__ float sigf(float x)   { return fast_rcp(1.f + __expf(-x)); }
__device__ __forceinline__ float tanhf_(float x) { return 1.f - 2.f * fast_rcp(1.f + __expf(2.f * x)); }

__device__ __forceinline__ unsigned packsplit(float v) {
  _Float16 hh = (_Float16)v;
  _Float16 hl = (_Float16)(v - (float)hh);
  unsigned short a = __builtin_bit_cast(unsigned short, hh);
  unsigned short b = __builtin_bit_cast(unsigned short, hl);
  return (unsigned)a | ((unsigned)b << 16);
}
__device__ __forceinline__ _Float16 f16lo(unsigned u) {
  return __builtin_bit_cast(_Float16, (unsigned short)(u & 0xffffu));
}
__device__ __forceinline__ _Float16 f16hi(unsigned u) {
  return __builtin_bit_cast(_Float16, (unsigned short)(u >> 16));
}
__device__ __forceinline__ void zfrag(f16x8 &f) {
  #pragma unroll
  for (int i = 0; i < 8; ++i) f[i] = (_Float16)0.f;
}
// load 8 consecutive f32 and split into hi/lo f16 fragments
__device__ __forceinline__ void wsplit8(const float* p, f16x8 &bh, f16x8 &bl) {
  float t0[8];
  *(float4*)&t0[0] = *(const float4*)&p[0];
  *(float4*)&t0[4] = *(const float4*)&p[4];
  #pragma unroll
  for (int i = 0; i < 8; ++i) {
    float v = t0[i];
    _Float16 h = (_Float16)v;
    bh[i] = h;
    bl[i] = (_Float16)(v - (float)h);
  }
}
// read 8 packed (hi|lo) u32 from an LDS h-plane -> hi/lo A-fragments
__device__ __forceinline__ void ldsAfrag(const unsigned* plane, int row, int k0,
                                         f16x8 &ah, f16x8 &al) {
  const uint4* p = (const uint4*)&plane[row * LSTRIDE + k0];
  uint4 a = p[0], b = p[1];
  unsigned u[8] = {a.x, a.y, a.z, a.w, b.x, b.y, b.z, b.w};
  #pragma unroll
  for (int i = 0; i < 8; ++i) { ah[i] = f16lo(u[i]); al[i] = f16hi(u[i]); }
}

__global__ __launch_bounds__(NTH, 2) void lstm2_mfma_kernel(
    const float* __restrict__ x,
    const float* __restrict__ Wih0, const float* __restrict__ Whh0,
    const float* __restrict__ bih0, const float* __restrict__ bhh0,
    const float* __restrict__ Wih1, const float* __restrict__ Whh1,
    const float* __restrict__ bih1, const float* __restrict__ bhh1,
    const float* __restrict__ W1, const float* __restrict__ b1,
    const float* __restrict__ W2, const float* __restrict__ b2,
    float* __restrict__ out)
{
  // 7 planes of layer-0 h history + 2 ping-pong planes for layer-1 h  (156672 B)
  __shared__ unsigned s_hist[TT][PLANE];
  __shared__ unsigned s_h2b[2][PLANE];

  const int tid  = threadIdx.x;
  const int l    = tid & 63;
  const int wave = tid >> 6;
  const int wm   = wave >> 2;       // 0..1 : row-half (32 rows)
  const int wn   = wave & 3;        // 0..3 : j-quarter (16 cols per gate)
  const int l15  = l & 15;
  const int lg   = l >> 4;          // 0..3 : k-group (A/B), row subgroup (C)
  const int jj   = wn * 16 + l15;   // hidden index 0..63 owned by this lane
  const int blk  = blockIdx.x;

  // weight fragments in VGPRs: [gate][ktile], hi+lo split
  f16x8 Bxh[4][2], Bxl[4][2], Bhh[4][2], Bhl[4][2];

  #pragma unroll 1
  for (int layer = 0; layer < 2; ++layer) {
    const float* Wi  = layer ? Wih1 : Wih0;
    const float* Wh  = layer ? Whh1 : Whh0;
    const float* bi  = layer ? bih1 : bih0;
    const float* bh_ = layer ? bhh1 : bhh0;
    const int Kin = layer ? HH : DD;

    // ---- stage weight fragments (registers; B[k][n] = W[n][k]) ----
    #pragma unroll
    for (int g = 0; g < 4; ++g) {
      int n = g * 64 + jj;
      #pragma unroll
      for (int kt = 0; kt < 2; ++kt) {
        int k0 = kt * 32 + lg * 8;
        if (k0 + 8 <= Kin) wsplit8(&Wi[n * Kin + k0], Bxh[g][kt], Bxl[g][kt]);
        else { zfrag(Bxh[g][kt]); zfrag(Bxl[g][kt]); }
        wsplit8(&Wh[n * HH + k0], Bhh[g][kt], Bhl[g][kt]);   // k0+8 <= 64 always
      }
    }
    f32x4 binit[4];
    #pragma unroll
    for (int g = 0; g < 4; ++g) {
      float bv = bi[g * 64 + jj] + bh_[g * 64 + jj];
      #pragma unroll
      for (int i = 0; i < 4; ++i) binit[g][i] = bv;
    }

    float cst[2][4];
    #pragma unroll
    for (int mt = 0; mt < 2; ++mt)
      #pragma unroll
      for (int r = 0; r < 4; ++r) cst[mt][r] = 0.f;

    #pragma unroll 1
    for (int t = 0; t < TT; ++t) {
      if (layer | t) __syncthreads();

      // stage FC weights into freed hist plane 1 (read last at layer-1 t==1)
      if (layer == 1 && t == 3) {
        float* wst = (float*)s_hist[1];
        for (int i = tid; i < 2113; i += NTH) {
          float v;
          if (i < 2048)      v = W1[i];
          else if (i < 2080) v = b1[i - 2048];
          else if (i < 2112) v = W2[i - 2080];
          else               v = b2[0];
          wst[i] = v;
        }
      }

      f32x4 acc[2][4];
      #pragma unroll
      for (int mt = 0; mt < 2; ++mt)
        #pragma unroll
        for (int g = 0; g < 4; ++g) acc[mt][g] = binit[g];

      #pragma unroll
      for (int mt = 0; mt < 2; ++mt) {
        int row = wm * 32 + mt * 16 + l15;   // A-operand row (local)

        // ---- input-side A fragments ----
        f16x8 ah[2], al[2];
        if (layer == 0) {
          const float* px = x + (blk * RB + row) * (TT * DD) + t * DD;
          #pragma unroll
          for (int kt = 0; kt < 2; ++kt) {
            int k0 = kt * 32 + lg * 8;
            if (k0 + 8 <= DD) {
              float tv[8];
              *(float4*)&tv[0] = *(const float4*)&px[k0];
              *(float4*)&tv[4] = *(const float4*)&px[k0 + 4];
              #pragma unroll
              for (int i = 0; i < 8; ++i) {
                float v = tv[i];
                _Float16 h = (_Float16)v;
                ah[kt][i] = h;
                al[kt][i] = (_Float16)(v - (float)h);
              }
            } else { zfrag(ah[kt]); zfrag(al[kt]); }
          }
        } else {
          #pragma unroll
          for (int kt = 0; kt < 2; ++kt)
            ldsAfrag(s_hist[t], row, kt * 32 + lg * 8, ah[kt], al[kt]);
        }
        #pragma unroll
        for (int g = 0; g < 4; ++g)
          #pragma unroll
          for (int kt = 0; kt < 2; ++kt) {
            MFMA16(acc[mt][g], ah[kt], Bxh[g][kt]);
            MFMA16(acc[mt][g], ah[kt], Bxl[g][kt]);
            MFMA16(acc[mt][g], al[kt], Bxh[g][kt]);
          }

        // ---- recurrent A fragments (h_{t-1}) ----
        if (t > 0) {
          f16x8 rh[2], rl[2];
          const unsigned* rplane = (layer == 0) ? s_hist[t - 1] : s_h2b[(t - 1) & 1];
          #pragma unroll
          for (int kt = 0; kt < 2; ++kt)
            ldsAfrag(rplane, row, kt * 32 + lg * 8, rh[kt], rl[kt]);
          #pragma unroll
          for (int g = 0; g < 4; ++g)
            #pragma unroll
            for (int kt = 0; kt < 2; ++kt) {
              MFMA16(acc[mt][g], rh[kt], Bhh[g][kt]);
              MFMA16(acc[mt][g], rh[kt], Bhl[g][kt]);
              MFMA16(acc[mt][g], rl[kt], Bhh[g][kt]);
            }
        }
      }

      // ---- epilogue: gates -> c,h ; write h to LDS ----
      #pragma unroll
      for (int mt = 0; mt < 2; ++mt) {
        #pragma unroll
        for (int r = 0; r < 4; ++r) {
          float ig = sigf(acc[mt][0][r]);
          float fg = sigf(acc[mt][1][r]);
          float gg = tanhf_(acc[mt][2][r]);
          float og = sigf(acc[mt][3][r]);
          float c  = fg * cst[mt][r] + ig * gg;
          cst[mt][r] = c;
          float h  = og * tanhf_(c);
          int rw = wm * 32 + mt * 16 + lg * 4 + r;   // C-layout row
          if (layer == 0)      s_hist[t][rw * LSTRIDE + jj] = packsplit(h);
          else if (t < TT - 1) s_h2b[t & 1][rw * LSTRIDE + jj] = packsplit(h);
          else ((float*)s_hist[0])[rw * LSTRIDE + jj] = h;   // final h2 as f32
        }
      }
    }
  }

  // ---- FC head ----
  __syncthreads();
  {
    const float* h2   = (const float*)s_hist[0];   // [64][LSTRIDE] f32
    const float* w1s  = (const float*)s_hist[1];   // W1|b1|W2|b2
    float* hidb       = (float*)s_hist[2];         // [64][36] f32

    int row = tid >> 3;
    int f0  = (tid & 7) * 4;
    float a4[4];
    #pragma unroll
    for (int q = 0; q < 4; ++q) a4[q] = w1s[2048 + f0 + q];
    #pragma unroll
    for (int k = 0; k < HH; k += 4) {
      float4 hv = *(const float4*)&h2[row * LSTRIDE + k];
      #pragma unroll
      for (int q = 0; q < 4; ++q) {
        float4 wv = *(const float4*)&w1s[(f0 + q) * HH + k];
        a4[q] += hv.x * wv.x + hv.y * wv.y + hv.z * wv.z + hv.w * wv.w;
      }
    }
    #pragma unroll
    for (int q = 0; q < 4; ++q) hidb[row * 36 + f0 + q] = fmaxf(a4[q], 0.f);
  }
  __syncthreads();
  if (tid < RB) {
    const float* w1s = (const float*)s_hist[1];
    const float* hidb = (const float*)s_hist[2];
    float a = w1s[2112];                          // b2
    #pragma unroll
    for (int k = 0; k < FCC; ++k) a += hidb[tid * 36 + k] * w1s[2080 + k];
    out[blk * RB + tid] = a;
  }
}

extern "C" void kernel_launch(void* const* d_in, const int* in_sizes, int n_in,
                              void* d_out, int out_size, void* d_ws, size_t ws_size,
                              hipStream_t stream) {
  const float* x    = (const float*)d_in[0];
  const float* Wih0 = (const float*)d_in[1];
  const float* Whh0 = (const float*)d_in[2];
  const float* bih0 = (const float*)d_in[3];
  const float* bhh0 = (const float*)d_in[4];
  const float* Wih1 = (const float*)d_in[5];
  const float* Whh1 = (const float*)d_in[6];
  const float* bih1 = (const float*)d_in[7];
  const float* bhh1 = (const float*)d_in[8];
  const float* W1   = (const float*)d_in[9];
  const float* b1   = (const float*)d_in[10];
  const float* W2   = (const float*)d_in[11];
  const float* b2   = (const float*)d_in[12];
  float* out = (float*)d_out;

  const int Btot = in_sizes[0] / (TT * DD);   // 32768
  dim3 grid(Btot / RB), block(NTH);
  lstm2_mfma_kernel<<<grid, block, 0, stream>>>(
      x, Wih0, Whh0, bih0, bhh0, Wih1, Whh1, bih1, bhh1, W1, b1, W2, b2, out);
}

// Round 3
// 131.193 us; speedup vs baseline: 4.2566x; 1.0661x over previous
//
#include <hip/hip_runtime.h>

#define TT 7
#define DD 40
#define HH 64
#define RB 16          // rows per block
#define NTH 256        // 4 waves (one per j-quarter)
#define HS 72          // u16 row stride in h planes (144 B = 9 x 16B groups, odd -> conflict-free b128)
#define PL (RB*HS)     // u16 elements per plane (1152; 2304 B)

typedef _Float16 f16x8 __attribute__((ext_vector_type(8)));
typedef float f32x4 __attribute__((ext_vector_type(4)));

#define MFMA16(acc, a, b) acc = __builtin_amdgcn_mfma_f32_16x16x32_f16(a, b, acc, 0, 0, 0)

__device__ __forceinline__ float fast_rcp(float x) { return __builtin_amdgcn_rcpf(x); }
__device__ __forceinline__ float sigf(float x)   { return fast_rcp(1.f + __expf(-x)); }
__device__ __forceinline__ float tanhf_(float x) { return 1.f - 2.f * fast_rcp(1.f + __expf(2.f * x)); }
__device__ __forceinline__ unsigned short u16c(_Float16 h) { return __builtin_bit_cast(unsigned short, h); }

__device__ __forceinline__ f16x8 zf() {
  f16x8 r;
  #pragma unroll
  for (int i = 0; i < 8; ++i) r[i] = (_Float16)0.f;
  return r;
}
// 8 consecutive f32 -> single f16 fragment (for weights)
__device__ __forceinline__ f16x8 cvt8(const float* p) {
  float4 a = *(const float4*)p, b = *(const float4*)(p + 4);
  f16x8 r;
  r[0] = (_Float16)a.x; r[1] = (_Float16)a.y; r[2] = (_Float16)a.z; r[3] = (_Float16)a.w;
  r[4] = (_Float16)b.x; r[5] = (_Float16)b.y; r[6] = (_Float16)b.z; r[7] = (_Float16)b.w;
  return r;
}
// 8 consecutive f32 -> hi/lo split f16 fragments (for activations)
__device__ __forceinline__ void split8(const float* p, f16x8 &hi, f16x8 &lo) {
  float t0[8];
  *(float4*)&t0[0] = *(const float4*)p;
  *(float4*)&t0[4] = *(const float4*)(p + 4);
  #pragma unroll
  for (int i = 0; i < 8; ++i) {
    _Float16 h = (_Float16)t0[i];
    hi[i] = h;
    lo[i] = (_Float16)(t0[i] - (float)h);
  }
}

__global__ __launch_bounds__(NTH, 4) void lstm2_mfma16_kernel(
    const float* __restrict__ x,
    const float* __restrict__ Wih0, const float* __restrict__ Whh0,
    const float* __restrict__ bih0, const float* __restrict__ bhh0,
    const float* __restrict__ Wih1, const float* __restrict__ Whh1,
    const float* __restrict__ bih1, const float* __restrict__ bhh1,
    const float* __restrict__ W1, const float* __restrict__ b1,
    const float* __restrict__ W2, const float* __restrict__ b2,
    float* __restrict__ out)
{
  // 29,952 B total -> 4+ blocks/CU alongside VGPR<=128
  __shared__ __align__(16) unsigned short s_hist[TT * PL];  // layer-0 h (hi), all t
  __shared__ __align__(16) unsigned short s_h0lo[2 * PL];   // layer-0 h (lo), ping-pong
  __shared__ __align__(16) unsigned short s_h2hi[2 * PL];   // layer-1 h (hi), ping-pong
  __shared__ __align__(16) unsigned short s_h2lo[2 * PL];   // layer-1 h (lo), ping-pong

  const int tid = threadIdx.x;
  const int l   = tid & 63;
  const int wn  = tid >> 6;        // j-quarter 0..3
  const int l15 = l & 15;
  const int lg  = l >> 4;          // k-group (A/B), C row subgroup
  const int jj  = wn * 16 + l15;   // hidden col owned by this lane
  const int blk = blockIdx.x;
  const int k0l = lg * 8;

  f16x8 Bx[4][2], Bh[4][2];        // single-f16 weight fragments
  float bias[4], cst[4];

  #pragma unroll 1
  for (int layer = 0; layer < 2; ++layer) {
    const float* Wi  = layer ? Wih1 : Wih0;
    const float* Wh  = layer ? Whh1 : Whh0;
    const float* bi  = layer ? bih1 : bih0;
    const float* bh_ = layer ? bhh1 : bhh0;
    const int Kin = layer ? HH : DD;

    #pragma unroll
    for (int g = 0; g < 4; ++g) {
      int n = g * 64 + jj;
      #pragma unroll
      for (int kt = 0; kt < 2; ++kt) {
        int k0 = kt * 32 + k0l;
        Bx[g][kt] = (k0 + 8 <= Kin) ? cvt8(&Wi[n * Kin + k0]) : zf();
        Bh[g][kt] = cvt8(&Wh[n * HH + k0]);
      }
      bias[g] = bi[n] + bh_[n];
      cst[g] = 0.f;                // reused as cst[r]; init all 4
    }

    #pragma unroll 1
    for (int t = 0; t < TT; ++t) {
      if (layer + t) __syncthreads();

      // stage FC weights into consumed hist planes 0..3.7 (read after final barrier)
      if (layer == 1 && t == 5) {
        float* wst = (float*)s_hist;
        for (int i = tid; i < 2113; i += NTH) {
          float v;
          if (i < 2048)      v = W1[i];
          else if (i < 2080) v = b1[i - 2048];
          else if (i < 2112) v = W2[i - 2080];
          else               v = b2[0];
          wst[i] = v;
        }
      }

      f32x4 acc[4];
      #pragma unroll
      for (int g = 0; g < 4; ++g) acc[g] = (f32x4){0.f, 0.f, 0.f, 0.f};

      // ---- input contribution ----
      if (layer == 0) {
        f16x8 xh[2], xl[2];
        const float* px = x + (blk * RB + l15) * (TT * DD) + t * DD;
        #pragma unroll
        for (int kt = 0; kt < 2; ++kt) {
          int k0 = kt * 32 + k0l;
          if (k0 + 8 <= DD) split8(px + k0, xh[kt], xl[kt]);
          else { xh[kt] = zf(); xl[kt] = zf(); }
        }
        #pragma unroll
        for (int g = 0; g < 4; ++g)
          #pragma unroll
          for (int kt = 0; kt < 2; ++kt) {
            MFMA16(acc[g], xh[kt], Bx[g][kt]);
            MFMA16(acc[g], xl[kt], Bx[g][kt]);
          }
      } else {
        const unsigned short* ip = s_hist + t * PL + l15 * HS;
        f16x8 ih0 = *(const f16x8*)(ip + k0l);
        f16x8 ih1 = *(const f16x8*)(ip + 32 + k0l);
        #pragma unroll
        for (int g = 0; g < 4; ++g) {
          MFMA16(acc[g], ih0, Bx[g][0]);
          MFMA16(acc[g], ih1, Bx[g][1]);
        }
      }

      // ---- recurrent contribution ----
      if (t > 0) {
        const unsigned short* hp =
            (layer == 0 ? s_hist + (t - 1) * PL : s_h2hi + ((t - 1) & 1) * PL) + l15 * HS;
        const unsigned short* lp =
            (layer == 0 ? s_h0lo + ((t - 1) & 1) * PL : s_h2lo + ((t - 1) & 1) * PL) + l15 * HS;
        f16x8 rh0 = *(const f16x8*)(hp + k0l);
        f16x8 rh1 = *(const f16x8*)(hp + 32 + k0l);
        f16x8 rl0 = *(const f16x8*)(lp + k0l);
        f16x8 rl1 = *(const f16x8*)(lp + 32 + k0l);
        #pragma unroll
        for (int g = 0; g < 4; ++g) {
          MFMA16(acc[g], rh0, Bh[g][0]);
          MFMA16(acc[g], rh1, Bh[g][1]);
          MFMA16(acc[g], rl0, Bh[g][0]);
          MFMA16(acc[g], rl1, Bh[g][1]);
        }
      }

      // ---- epilogue ----
      #pragma unroll
      for (int r = 0; r < 4; ++r) {
        float ig = sigf(acc[0][r] + bias[0]);
        float fg = sigf(acc[1][r] + bias[1]);
        float gg = tanhf_(acc[2][r] + bias[2]);
        float og = sigf(acc[3][r] + bias[3]);
        float c  = fg * cst[r] + ig * gg;
        cst[r] = c;
        float h  = og * tanhf_(c);
        int row = lg * 4 + r;
        _Float16 hh = (_Float16)h;
        _Float16 hl = (_Float16)(h - (float)hh);
        if (layer == 0) {
          s_hist[t * PL + row * HS + jj]       = u16c(hh);
          s_h0lo[(t & 1) * PL + row * HS + jj] = u16c(hl);
        } else if (t < TT - 1) {
          s_h2hi[(t & 1) * PL + row * HS + jj] = u16c(hh);
          s_h2lo[(t & 1) * PL + row * HS + jj] = u16c(hl);
        } else {
          ((float*)(s_hist + 4 * PL))[row * 68 + jj] = h;  // final h2 f32 (planes 4-5)
        }
      }
    }
  }

  // ---- FC head ----
  __syncthreads();
  {
    const float* wfc = (const float*)s_hist;             // W1|b1|W2|b2 (planes 0-3.7)
    const float* h2f = (const float*)(s_hist + 4 * PL);  // [16][68] f32
    float* hid = (float*)s_h0lo;                         // [16][36] f32
    int row = tid >> 4;
    int f0  = (tid & 15) * 2;
    float a0 = wfc[2048 + f0], a1 = wfc[2048 + f0 + 1];
    #pragma unroll
    for (int kk = 0; kk < HH; kk += 4) {
      float4 hv = *(const float4*)&h2f[row * 68 + kk];
      float4 w0 = *(const float4*)&wfc[(f0    ) * HH + kk];
      float4 w1 = *(const float4*)&wfc[(f0 + 1) * HH + kk];
      a0 += hv.x * w0.x + hv.y * w0.y + hv.z * w0.z + hv.w * w0.w;
      a1 += hv.x * w1.x + hv.y * w1.y + hv.z * w1.z + hv.w * w1.w;
    }
    hid[row * 36 + f0]     = fmaxf(a0, 0.f);
    hid[row * 36 + f0 + 1] = fmaxf(a1, 0.f);
  }
  __syncthreads();
  if (tid < RB) {
    const float* wfc = (const float*)s_hist;
    const float* hid = (const float*)s_h0lo;
    float a = wfc[2112];
    #pragma unroll
    for (int kk = 0; kk < 32; ++kk) a += hid[tid * 36 + kk] * wfc[2080 + kk];
    out[blk * RB + tid] = a;
  }
}

extern "C" void kernel_launch(void* const* d_in, const int* in_sizes, int n_in,
                              void* d_out, int out_size, void* d_ws, size_t ws_size,
                              hipStream_t stream) {
  const float* x    = (const float*)d_in[0];
  const float* Wih0 = (const float*)d_in[1];
  const float* Whh0 = (const float*)d_in[2];
  const float* bih0 = (const float*)d_in[3];
  const float* bhh0 = (const float*)d_in[4];
  const float* Wih1 = (const float*)d_in[5];
  const float* Whh1 = (const float*)d_in[6];
  const float* bih1 = (const float*)d_in[7];
  const float* bhh1 = (const float*)d_in[8];
  const float* W1   = (const float*)d_in[9];
  const float* b1   = (const float*)d_in[10];
  const float* W2   = (const float*)d_in[11];
  const float* b2   = (const float*)d_in[12];
  float* out = (float*)d_out;

  const int Btot = in_sizes[0] / (TT * DD);   // 32768
  dim3 grid(Btot / RB), block(NTH);
  lstm2_mfma16_kernel<<<grid, block, 0, stream>>>(
      x, Wih0, Whh0, bih0, bhh0, Wih1, Whh1, bih1, bhh1, W1, b1, W2, b2, out);
}